// Round 18
// baseline (128.807 us; speedup 1.0000x reference)
//
#include <hip/hip_runtime.h>
#include <hip/hip_bf16.h>
#include <math.h>

#define DD 64
#define NN 512
#define LL 1024
#define EPSF 1e-5f
#define NCH 32   // n-chunks (xbar partials per l)

typedef short short8 __attribute__((ext_vector_type(8)));
typedef float f32x4 __attribute__((ext_vector_type(4)));

// pure-C round-to-nearest-even bf16 (bits in low 16)
static __device__ __forceinline__ unsigned bf16_rne(float f) {
  unsigned u = __float_as_uint(f);
  return (u + 0x7FFFu + ((u >> 16) & 1u)) >> 16;
}
static __device__ __forceinline__ float bf16_hi_f(float f) {
  unsigned u = __float_as_uint(f);
  return __uint_as_float((u + 0x7FFFu + ((u >> 16) & 1u)) & 0xFFFF0000u);
}
// packed RNE convert via builtin (compiler-legal v_cvt_pk_bf16_f32)
static __device__ __forceinline__ unsigned cvtpk2(float a, float b) {
  __hip_bfloat162 h = __float22bfloat162_rn(make_float2(a, b));
  union { __hip_bfloat162 h2; unsigned u; } c;
  c.h2 = h;
  return c.u;
}
static __device__ __forceinline__ short8 pack8(unsigned a, unsigned b,
                                               unsigned c, unsigned d) {
  union { uint4 u; short8 s; } x;
  x.u = make_uint4(a, b, c, d);
  return x.s;
}
// XOR-swizzled short index into a [128][64]-short LDS tile
// (verified R14: SQ_LDS_BANK_CONFLICT 1.05M -> 0)
static __device__ __forceinline__ int swz(int row, int soff) {
  return row * 64 + (soff ^ ((row & 7) << 3));
}

// ---------------------------------------------------------------------------
// Kernel A (R12, proven): block = 16 l x 16 n rows; thread = one row in regs
// (X[64]); LN stats -> 8B stats store -> fused d-loop (xn, k/v FMAs) ->
// k/v store -> butterfly -> xbar partial. launch_bounds(256,4) = healthy.
// ---------------------------------------------------------------------------
__global__ __launch_bounds__(256, 4) void kA(
    const float* __restrict__ msa, const float* __restrict__ lnw, const float* __restrict__ lnb,
    const float* __restrict__ Wk, const float* __restrict__ Wv,
    float* __restrict__ kb, float* __restrict__ vb, float* __restrict__ xbarP,
    float* __restrict__ stats)
{
  __shared__ float xc[4][16][68];
  const int t = threadIdx.x;
  const int lane = t & 63;
  const int w = t >> 6;
  const int l_loc = t & 15;
  const int n_loc = t >> 4;
  const int lt = blockIdx.x & 63;
  const int nc = blockIdx.x >> 6;
  const int l0 = lt * 16;
  const int n = nc * 16 + n_loc;
  const int l = l0 + l_loc;

  float X[DD];
  {
    const float4* rp = (const float4*)(msa + ((size_t)n * LL + l) * DD);
#pragma unroll
    for (int i = 0; i < 16; ++i) {
      const float4 f = rp[i];
      X[4*i+0] = f.x; X[4*i+1] = f.y; X[4*i+2] = f.z; X[4*i+3] = f.w;
    }
  }

  float s = 0.f, s2 = 0.f;
#pragma unroll
  for (int d = 0; d < DD; ++d) { s += X[d]; s2 = fmaf(X[d], X[d], s2); }
  const float mu = s * (1.f / DD);
  const float rs = rsqrtf(fmaf(-mu, mu, s2 * (1.f / DD)) + EPSF);

  {
    float2* sp = (float2*)(stats + ((size_t)n * LL + l) * 2);
    *sp = make_float2(rs, -mu * rs);
  }

  float ka[8], va[8];
#pragma unroll
  for (int j = 0; j < 8; ++j) { ka[j] = 0.f; va[j] = 0.f; }
#pragma unroll
  for (int d = 0; d < DD; ++d) {
    const float xn = fmaf((X[d] - mu) * rs, lnw[d], lnb[d]);
    X[d] = xn;
#pragma unroll
    for (int j = 0; j < 8; ++j) {
      ka[j] = fmaf(xn, Wk[d * 8 + j], ka[j]);
      va[j] = fmaf(xn, Wv[d * 8 + j], va[j]);
    }
  }

  {
    float4* kp = (float4*)(kb + ((size_t)l * NN + n) * 8);
    float4* vp = (float4*)(vb + ((size_t)l * NN + n) * 8);
    kp[0] = make_float4(ka[0], ka[1], ka[2], ka[3]);
    kp[1] = make_float4(ka[4], ka[5], ka[6], ka[7]);
    vp[0] = make_float4(va[0], va[1], va[2], va[3]);
    vp[1] = make_float4(va[4], va[5], va[6], va[7]);
  }

  {
    const bool hi1 = (lane & 16) != 0;
#pragma unroll
    for (int k = 0; k < 32; ++k) {
      const float keep = hi1 ? X[k + 32] : X[k];
      const float send = hi1 ? X[k] : X[k + 32];
      X[k] = keep + __shfl_xor(send, 16);
    }
    const bool hi2 = (lane & 32) != 0;
#pragma unroll
    for (int k = 0; k < 16; ++k) {
      const float keep = hi2 ? X[k + 16] : X[k];
      const float send = hi2 ? X[k] : X[k + 16];
      X[k] = keep + __shfl_xor(send, 32);
    }
  }
  const int d0i = ((lane >> 4) & 1) * 32 + (lane >> 5) * 16;
#pragma unroll
  for (int k = 0; k < 16; ++k) xc[w][l_loc][d0i + k] = X[k];
  __syncthreads();

#pragma unroll
  for (int j = 0; j < 4; ++j) {
    const int c = t * 4 + j;
    const int ll = c >> 6, d = c & 63;
    const float sv = xc[0][ll][d] + xc[1][ll][d] + xc[2][ll][d] + xc[3][ll][d];
    xbarP[((size_t)(l0 + ll) * NCH + nc) * DD + d] = sv;
  }
}

// ---------------------------------------------------------------------------
// Kernel B v2 (R13, proven): blocks 0-15 also pack Wg/Wout B-fragments;
// xbar reduce parallel over 8 waves; q/scores/softmax/PV per head-wave;
// writes obT[d][l].
// ---------------------------------------------------------------------------
__global__ __launch_bounds__(512) void kB(
    const float* __restrict__ kb, const float* __restrict__ vb,
    const float* __restrict__ xbarP, const float* __restrict__ Wq,
    const float* __restrict__ Wg, const float* __restrict__ Wout,
    unsigned* __restrict__ Bpk, float* __restrict__ obT)
{
  __shared__ float xbL[DD];
  __shared__ float qs[DD];
  __shared__ float red[8][68];
  __shared__ float ks[NN * 9];
  __shared__ float vs[NN * 9];
  const int l = blockIdx.x;
  const int t = threadIdx.x;
  const int h = t >> 6;          // wave id == head
  const int lane = t & 63;

  if (blockIdx.x < 16) {
    const int idx = blockIdx.x * 512 + t;   // 0..8191
    const int e2   = idx & 3;
    const int plane = (idx >> 2) & 63;
    const int ctkt = (idx >> 8) & 7;
    const int hh   = (idx >> 11) & 1;
    const int mv   = (idx >> 12) & 1;
    const int col  = ((ctkt >> 1) << 4) | (plane & 15);
    const int k0   = ((ctkt & 1) << 5) + ((plane >> 4) << 3) + (e2 << 1);
    const float* W = mv ? Wout : Wg;
    const float w0 = W[k0 * DD + col];
    const float w1 = W[(k0 + 1) * DD + col];
    unsigned b0, b1;
    if (hh == 0) { b0 = bf16_rne(w0); b1 = bf16_rne(w1); }
    else         { b0 = bf16_rne(w0 - bf16_hi_f(w0)); b1 = bf16_rne(w1 - bf16_hi_f(w1)); }
    Bpk[idx] = b0 | (b1 << 16);
  }

  const float* kl = kb + (size_t)l * NN * 8;
  const float* vl = vb + (size_t)l * NN * 8;
#pragma unroll
  for (int i = 0; i < 8; ++i) {
    const int idx = i * 512 + t;
    const int n = idx >> 3, j = idx & 7;
    ks[n*9 + j] = kl[idx];
    vs[n*9 + j] = vl[idx];
  }
  {
    float sxb = 0.f;
#pragma unroll
    for (int i = 0; i < 4; ++i)
      sxb += xbarP[((size_t)l * NCH + (h + 8 * i)) * DD + lane];
    red[h][lane] = sxb;
  }
  __syncthreads();
  if (t < DD) {
    const float sv = ((red[0][t] + red[1][t]) + (red[2][t] + red[3][t]))
                   + ((red[4][t] + red[5][t]) + (red[6][t] + red[7][t]));
    xbL[t] = sv * (1.f / NN);
  }
  __syncthreads();
  if (t < DD) {
    float acc = 0.f;
    for (int d = 0; d < DD; ++d) acc = fmaf(xbL[d], Wq[d*DD + t], acc);
    qs[t] = acc * 0.35355339059327373f;   // 1/sqrt(DH)
  }
  __syncthreads();

  float sc[8];
  float m = -1e30f;
#pragma unroll
  for (int i = 0; i < 8; ++i) {
    const int n = i * 64 + lane;
    float s = 0.f;
#pragma unroll
    for (int d = 0; d < 8; ++d) s = fmaf(qs[h*8 + d], ks[n*9 + d], s);
    sc[i] = s;
    m = fmaxf(m, s);
  }
#pragma unroll
  for (int off = 32; off; off >>= 1) m = fmaxf(m, __shfl_xor(m, off));
  float ssum = 0.f;
#pragma unroll
  for (int i = 0; i < 8; ++i) { sc[i] = __expf(sc[i] - m); ssum += sc[i]; }
#pragma unroll
  for (int off = 32; off; off >>= 1) ssum += __shfl_xor(ssum, off);
  const float inv = 1.f / ssum;

  float oacc[8];
#pragma unroll
  for (int d = 0; d < 8; ++d) oacc[d] = 0.f;
#pragma unroll
  for (int i = 0; i < 8; ++i) {
    const int n = i * 64 + lane;
#pragma unroll
    for (int d = 0; d < 8; ++d) oacc[d] = fmaf(sc[i], vs[n*9 + d], oacc[d]);
  }
#pragma unroll
  for (int d = 0; d < 8; ++d) {
#pragma unroll
    for (int off = 32; off; off >>= 1) oacc[d] += __shfl_xor(oacc[d], off);
  }
  if (lane == 0) {
#pragma unroll
    for (int d = 0; d < 8; ++d)
      obT[(size_t)(h * 8 + d) * LL + l] = oacc[d] * inv;
  }
}

// ---------------------------------------------------------------------------
// Kernel C v12 = R16's v10 (128 rows/block, 256 thr, (256,4), swizzled
// TH/TL, rcp sigmoid, cvtpk2) + HOISTED obT gather: the 8 scattered float4
// L2 loads are issued at kernel top (they depend on nothing computed here)
// and pinned with sched_barrier(0) so their ~200-400cy latency overlaps the
// whole mv1 phase instead of sitting serially between mv1 and sigmoid.
// ---------------------------------------------------------------------------
__global__ __launch_bounds__(256, 4) void kC(
    const float* __restrict__ msa, const float* __restrict__ stats,
    const float* __restrict__ lnw, const float* __restrict__ lnb,
    const unsigned* __restrict__ Bpk, const float* __restrict__ bg,
    const float* __restrict__ obT, const float* __restrict__ bout,
    float* __restrict__ out)
{
  __shared__ unsigned short TH[128 * 64];  // 16 KB (t hi), XOR-swizzled
  __shared__ unsigned short TL[128 * 64];  // 16 KB (t lo), XOR-swizzled
  const int t = threadIdx.x;
  const int lane = t & 63;
  const int w = t >> 6;
  const int rbase = 32 * w;
  const size_t R0 = (size_t)blockIdx.x * 128;

  const short8* Bp = (const short8*)Bpk;   // frag*64 + lane

  // ---- HOISTED: gate-o gather (independent of all kC compute) ----
  float4 ov[2][4];
#pragma unroll
  for (int rt = 0; rt < 2; ++rt) {
    const int rl0 = rbase + rt * 16 + ((lane >> 4) << 2);
    const int li0 = (int)((R0 + rl0) & (LL - 1));
#pragma unroll
    for (int ct = 0; ct < 4; ++ct) {
      const int col = ct * 16 + (lane & 15);
      ov[rt][ct] = *(const float4*)&obT[(size_t)col * LL + li0];
    }
  }
  __builtin_amdgcn_sched_barrier(0);   // pin these loads at the top

  f32x4 acc[2][4];
#pragma unroll
  for (int rt = 0; rt < 2; ++rt)
#pragma unroll
    for (int ct = 0; ct < 4; ++ct) acc[rt][ct] = f32x4{0.f, 0.f, 0.f, 0.f};

  // ---- mv1: A-frags from raw msa + stats ----
  {
    short8 ah[2][2];
#pragma unroll
    for (int rt = 0; rt < 2; ++rt) {
      const size_t ar = R0 + rbase + rt * 16 + (lane & 15);
      const int kg = (lane >> 4) * 8;
      const float2 ab = *(const float2*)&stats[ar * 2];
      const float aa = ab.x, bb = ab.y;
#pragma unroll
      for (int hh = 0; hh < 2; ++hh) {
        const int d0 = kg + hh * 32;
        const float4 f0 = *(const float4*)&msa[ar * DD + d0];
        const float4 f1 = *(const float4*)&msa[ar * DD + d0 + 4];
        const float4 w0 = *(const float4*)&lnw[d0];
        const float4 w1 = *(const float4*)&lnw[d0 + 4];
        const float4 b0 = *(const float4*)&lnb[d0];
        const float4 b1 = *(const float4*)&lnb[d0 + 4];
        const unsigned q0 = cvtpk2(fmaf(fmaf(f0.x, aa, bb), w0.x, b0.x),
                                   fmaf(fmaf(f0.y, aa, bb), w0.y, b0.y));
        const unsigned q1 = cvtpk2(fmaf(fmaf(f0.z, aa, bb), w0.z, b0.z),
                                   fmaf(fmaf(f0.w, aa, bb), w0.w, b0.w));
        const unsigned q2 = cvtpk2(fmaf(fmaf(f1.x, aa, bb), w1.x, b1.x),
                                   fmaf(fmaf(f1.y, aa, bb), w1.y, b1.y));
        const unsigned q3 = cvtpk2(fmaf(fmaf(f1.z, aa, bb), w1.z, b1.z),
                                   fmaf(fmaf(f1.w, aa, bb), w1.w, b1.w));
        ah[rt][hh] = pack8(q0, q1, q2, q3);
      }
    }
#pragma unroll
    for (int ct = 0; ct < 4; ++ct) {
      const short8 bh0 = Bp[(0 * 8 + ct * 2 + 0) * 64 + lane];
      const short8 bh1 = Bp[(0 * 8 + ct * 2 + 1) * 64 + lane];
      const short8 bl0 = Bp[(1 * 8 + ct * 2 + 0) * 64 + lane];
      const short8 bl1 = Bp[(1 * 8 + ct * 2 + 1) * 64 + lane];
#pragma unroll
      for (int rt = 0; rt < 2; ++rt) {
        f32x4 c = acc[rt][ct];
        c = __builtin_amdgcn_mfma_f32_16x16x32_bf16(ah[rt][0], bh0, c, 0, 0, 0);
        c = __builtin_amdgcn_mfma_f32_16x16x32_bf16(ah[rt][1], bh1, c, 0, 0, 0);
        c = __builtin_amdgcn_mfma_f32_16x16x32_bf16(ah[rt][0], bl0, c, 0, 0, 0);
        c = __builtin_amdgcn_mfma_f32_16x16x32_bf16(ah[rt][1], bl1, c, 0, 0, 0);
        acc[rt][ct] = c;
      }
    }
  }

  // ---- sigmoid * o -> t, hi/lo split into swizzled TH/TL (wave-private) ----
#pragma unroll
  for (int rt = 0; rt < 2; ++rt) {
    const int rl0 = rbase + rt * 16 + ((lane >> 4) << 2);
#pragma unroll
    for (int ct = 0; ct < 4; ++ct) {
      const int col = ct * 16 + (lane & 15);
      const float bgc = bg[col];
      const float tv0 = ov[rt][ct].x * __builtin_amdgcn_rcpf(1.f + __expf(-(acc[rt][ct][0] + bgc)));
      const float tv1 = ov[rt][ct].y * __builtin_amdgcn_rcpf(1.f + __expf(-(acc[rt][ct][1] + bgc)));
      const float tv2 = ov[rt][ct].z * __builtin_amdgcn_rcpf(1.f + __expf(-(acc[rt][ct][2] + bgc)));
      const float tv3 = ov[rt][ct].w * __builtin_amdgcn_rcpf(1.f + __expf(-(acc[rt][ct][3] + bgc)));
      const unsigned ph01 = cvtpk2(tv0, tv1);
      const unsigned ph23 = cvtpk2(tv2, tv3);
      const float h0 = __uint_as_float(ph01 << 16);
      const float h1 = __uint_as_float(ph01 & 0xFFFF0000u);
      const float h2 = __uint_as_float(ph23 << 16);
      const float h3 = __uint_as_float(ph23 & 0xFFFF0000u);
      const unsigned pl01 = cvtpk2(tv0 - h0, tv1 - h1);
      const unsigned pl23 = cvtpk2(tv2 - h2, tv3 - h3);
      TH[swz(rl0 + 0, col)] = (unsigned short)ph01;
      TH[swz(rl0 + 1, col)] = (unsigned short)(ph01 >> 16);
      TH[swz(rl0 + 2, col)] = (unsigned short)ph23;
      TH[swz(rl0 + 3, col)] = (unsigned short)(ph23 >> 16);
      TL[swz(rl0 + 0, col)] = (unsigned short)pl01;
      TL[swz(rl0 + 1, col)] = (unsigned short)(pl01 >> 16);
      TL[swz(rl0 + 2, col)] = (unsigned short)pl23;
      TL[swz(rl0 + 3, col)] = (unsigned short)(pl23 >> 16);
    }
  }
  // no barrier: wave-private rows

  // ---- mv2: out = t @ Wout + bout (3-term) ----
#pragma unroll
  for (int rt = 0; rt < 2; ++rt)
#pragma unroll
    for (int ct = 0; ct < 4; ++ct) {
      const float bo = bout[ct * 16 + (lane & 15)];
      acc[rt][ct] = f32x4{bo, bo, bo, bo};
    }
  {
    short8 ah[2][2], al[2][2];
#pragma unroll
    for (int rt = 0; rt < 2; ++rt) {
      const int ar = rbase + rt * 16 + (lane & 15);
      const int kg = (lane >> 4) * 8;
      ah[rt][0] = *(const short8*)&TH[swz(ar, kg)];
      ah[rt][1] = *(const short8*)&TH[swz(ar, kg + 32)];
      al[rt][0] = *(const short8*)&TL[swz(ar, kg)];
      al[rt][1] = *(const short8*)&TL[swz(ar, kg + 32)];
    }
#pragma unroll
    for (int ct = 0; ct < 4; ++ct) {
      const short8 bh0 = Bp[(2 * 8 + ct * 2 + 0) * 64 + lane];
      const short8 bh1 = Bp[(2 * 8 + ct * 2 + 1) * 64 + lane];
      const short8 bl0 = Bp[(3 * 8 + ct * 2 + 0) * 64 + lane];
      const short8 bl1 = Bp[(3 * 8 + ct * 2 + 1) * 64 + lane];
#pragma unroll
      for (int rt = 0; rt < 2; ++rt) {
        f32x4 c = acc[rt][ct];
        c = __builtin_amdgcn_mfma_f32_16x16x32_bf16(ah[rt][0], bh0, c, 0, 0, 0);
        c = __builtin_amdgcn_mfma_f32_16x16x32_bf16(ah[rt][1], bh1, c, 0, 0, 0);
        c = __builtin_amdgcn_mfma_f32_16x16x32_bf16(ah[rt][0], bl0, c, 0, 0, 0);
        c = __builtin_amdgcn_mfma_f32_16x16x32_bf16(ah[rt][1], bl1, c, 0, 0, 0);
        c = __builtin_amdgcn_mfma_f32_16x16x32_bf16(al[rt][0], bh0, c, 0, 0, 0);
        c = __builtin_amdgcn_mfma_f32_16x16x32_bf16(al[rt][1], bh1, c, 0, 0, 0);
        acc[rt][ct] = c;
      }
    }
  }

#pragma unroll
  for (int rt = 0; rt < 2; ++rt) {
#pragma unroll
    for (int j = 0; j < 4; ++j) {
      const size_t rg = R0 + rbase + rt * 16 + ((lane >> 4) << 2) + j;
#pragma unroll
      for (int ct = 0; ct < 4; ++ct)
        out[rg * DD + ct * 16 + (lane & 15)] = acc[rt][ct][j];
    }
  }
}

// ---------------------------------------------------------------------------
extern "C" void kernel_launch(void* const* d_in, const int* in_sizes, int n_in,
                              void* d_out, int out_size, void* d_ws, size_t ws_size,
                              hipStream_t stream)
{
  const float* msa  = (const float*)d_in[0];
  const float* lnw  = (const float*)d_in[1];
  const float* lnb  = (const float*)d_in[2];
  const float* Wq   = (const float*)d_in[3];
  const float* Wk   = (const float*)d_in[4];
  const float* Wv   = (const float*)d_in[5];
  const float* Wg   = (const float*)d_in[6];
  const float* bg   = (const float*)d_in[7];
  const float* Wout = (const float*)d_in[8];
  const float* bout = (const float*)d_in[9];
  float* out = (float*)d_out;

  float* kb    = (float*)d_ws;                        // (L, N, 8)  16 MB
  float* vb    = kb + (size_t)LL * NN * 8;            // (L, N, 8)  16 MB
  float* xbarP = vb + (size_t)LL * NN * 8;            // (L, 32, 64) 8 MB
  float* obT   = xbarP + (size_t)LL * NCH * DD;       // (64, L)   256 KB
  unsigned* Bpk = (unsigned*)(obT + (size_t)DD * LL); // 32 KB packed weights
  float* stats = (float*)(Bpk + 8192);                // (N*L, 2)  4 MB

  kA<<<64 * NCH, 256, 0, stream>>>(msa, lnw, lnb, Wk, Wv, kb, vb, xbarP, stats);
  kB<<<LL, 512, 0, stream>>>(kb, vb, xbarP, Wq, Wg, Wout, Bpk, obT);
  kC<<<(NN * LL) / 128, 256, 0, stream>>>(msa, stats, lnw, lnb, Bpk, bg, obT, bout, out);
}

// Round 19
// 121.097 us; speedup vs baseline: 1.0637x; 1.0637x over previous
//
#include <hip/hip_runtime.h>
#include <hip/hip_bf16.h>
#include <math.h>

#define DD 64
#define NN 512
#define LL 1024
#define EPSF 1e-5f
#define NCH 32   // n-chunks (xbar partials per l)

typedef short short8 __attribute__((ext_vector_type(8)));
typedef float f32x4 __attribute__((ext_vector_type(4)));

// pure-C round-to-nearest-even bf16 (bits in low 16)
static __device__ __forceinline__ unsigned bf16_rne(float f) {
  unsigned u = __float_as_uint(f);
  return (u + 0x7FFFu + ((u >> 16) & 1u)) >> 16;
}
static __device__ __forceinline__ float bf16_hi_f(float f) {
  unsigned u = __float_as_uint(f);
  return __uint_as_float((u + 0x7FFFu + ((u >> 16) & 1u)) & 0xFFFF0000u);
}
// packed RNE convert via builtin (compiler-legal v_cvt_pk_bf16_f32)
static __device__ __forceinline__ unsigned cvtpk2(float a, float b) {
  __hip_bfloat162 h = __float22bfloat162_rn(make_float2(a, b));
  union { __hip_bfloat162 h2; unsigned u; } c;
  c.h2 = h;
  return c.u;
}
static __device__ __forceinline__ short8 pack8(unsigned a, unsigned b,
                                               unsigned c, unsigned d) {
  union { uint4 u; short8 s; } x;
  x.u = make_uint4(a, b, c, d);
  return x.s;
}
// XOR-swizzled short index into a [128][64]-short LDS tile
// (verified R14: SQ_LDS_BANK_CONFLICT 1.05M -> 0)
static __device__ __forceinline__ int swz(int row, int soff) {
  return row * 64 + (soff ^ ((row & 7) << 3));
}

// ---------------------------------------------------------------------------
// Kernel A (R12, proven): block = 16 l x 16 n rows; thread = one row in regs
// (X[64]); LN stats -> 8B stats store -> fused d-loop (xn, k/v FMAs) ->
// k/v store -> butterfly -> xbar partial. launch_bounds(256,4) = healthy.
// ---------------------------------------------------------------------------
__global__ __launch_bounds__(256, 4) void kA(
    const float* __restrict__ msa, const float* __restrict__ lnw, const float* __restrict__ lnb,
    const float* __restrict__ Wk, const float* __restrict__ Wv,
    float* __restrict__ kb, float* __restrict__ vb, float* __restrict__ xbarP,
    float* __restrict__ stats)
{
  __shared__ float xc[4][16][68];
  const int t = threadIdx.x;
  const int lane = t & 63;
  const int w = t >> 6;
  const int l_loc = t & 15;
  const int n_loc = t >> 4;
  const int lt = blockIdx.x & 63;
  const int nc = blockIdx.x >> 6;
  const int l0 = lt * 16;
  const int n = nc * 16 + n_loc;
  const int l = l0 + l_loc;

  float X[DD];
  {
    const float4* rp = (const float4*)(msa + ((size_t)n * LL + l) * DD);
#pragma unroll
    for (int i = 0; i < 16; ++i) {
      const float4 f = rp[i];
      X[4*i+0] = f.x; X[4*i+1] = f.y; X[4*i+2] = f.z; X[4*i+3] = f.w;
    }
  }

  float s = 0.f, s2 = 0.f;
#pragma unroll
  for (int d = 0; d < DD; ++d) { s += X[d]; s2 = fmaf(X[d], X[d], s2); }
  const float mu = s * (1.f / DD);
  const float rs = rsqrtf(fmaf(-mu, mu, s2 * (1.f / DD)) + EPSF);

  {
    float2* sp = (float2*)(stats + ((size_t)n * LL + l) * 2);
    *sp = make_float2(rs, -mu * rs);
  }

  float ka[8], va[8];
#pragma unroll
  for (int j = 0; j < 8; ++j) { ka[j] = 0.f; va[j] = 0.f; }
#pragma unroll
  for (int d = 0; d < DD; ++d) {
    const float xn = fmaf((X[d] - mu) * rs, lnw[d], lnb[d]);
    X[d] = xn;
#pragma unroll
    for (int j = 0; j < 8; ++j) {
      ka[j] = fmaf(xn, Wk[d * 8 + j], ka[j]);
      va[j] = fmaf(xn, Wv[d * 8 + j], va[j]);
    }
  }

  {
    float4* kp = (float4*)(kb + ((size_t)l * NN + n) * 8);
    float4* vp = (float4*)(vb + ((size_t)l * NN + n) * 8);
    kp[0] = make_float4(ka[0], ka[1], ka[2], ka[3]);
    kp[1] = make_float4(ka[4], ka[5], ka[6], ka[7]);
    vp[0] = make_float4(va[0], va[1], va[2], va[3]);
    vp[1] = make_float4(va[4], va[5], va[6], va[7]);
  }

  {
    const bool hi1 = (lane & 16) != 0;
#pragma unroll
    for (int k = 0; k < 32; ++k) {
      const float keep = hi1 ? X[k + 32] : X[k];
      const float send = hi1 ? X[k] : X[k + 32];
      X[k] = keep + __shfl_xor(send, 16);
    }
    const bool hi2 = (lane & 32) != 0;
#pragma unroll
    for (int k = 0; k < 16; ++k) {
      const float keep = hi2 ? X[k + 16] : X[k];
      const float send = hi2 ? X[k] : X[k + 16];
      X[k] = keep + __shfl_xor(send, 32);
    }
  }
  const int d0i = ((lane >> 4) & 1) * 32 + (lane >> 5) * 16;
#pragma unroll
  for (int k = 0; k < 16; ++k) xc[w][l_loc][d0i + k] = X[k];
  __syncthreads();

#pragma unroll
  for (int j = 0; j < 4; ++j) {
    const int c = t * 4 + j;
    const int ll = c >> 6, d = c & 63;
    const float sv = xc[0][ll][d] + xc[1][ll][d] + xc[2][ll][d] + xc[3][ll][d];
    xbarP[((size_t)(l0 + ll) * NCH + nc) * DD + d] = sv;
  }
}

// ---------------------------------------------------------------------------
// Kernel B v2 (R13, proven): blocks 0-15 also pack Wg/Wout B-fragments;
// xbar reduce parallel over 8 waves; q/scores/softmax/PV per head-wave;
// writes obT[d][l].
// ---------------------------------------------------------------------------
__global__ __launch_bounds__(512) void kB(
    const float* __restrict__ kb, const float* __restrict__ vb,
    const float* __restrict__ xbarP, const float* __restrict__ Wq,
    const float* __restrict__ Wg, const float* __restrict__ Wout,
    unsigned* __restrict__ Bpk, float* __restrict__ obT)
{
  __shared__ float xbL[DD];
  __shared__ float qs[DD];
  __shared__ float red[8][68];
  __shared__ float ks[NN * 9];
  __shared__ float vs[NN * 9];
  const int l = blockIdx.x;
  const int t = threadIdx.x;
  const int h = t >> 6;          // wave id == head
  const int lane = t & 63;

  if (blockIdx.x < 16) {
    const int idx = blockIdx.x * 512 + t;   // 0..8191
    const int e2   = idx & 3;
    const int plane = (idx >> 2) & 63;
    const int ctkt = (idx >> 8) & 7;
    const int hh   = (idx >> 11) & 1;
    const int mv   = (idx >> 12) & 1;
    const int col  = ((ctkt >> 1) << 4) | (plane & 15);
    const int k0   = ((ctkt & 1) << 5) + ((plane >> 4) << 3) + (e2 << 1);
    const float* W = mv ? Wout : Wg;
    const float w0 = W[k0 * DD + col];
    const float w1 = W[(k0 + 1) * DD + col];
    unsigned b0, b1;
    if (hh == 0) { b0 = bf16_rne(w0); b1 = bf16_rne(w1); }
    else         { b0 = bf16_rne(w0 - bf16_hi_f(w0)); b1 = bf16_rne(w1 - bf16_hi_f(w1)); }
    Bpk[idx] = b0 | (b1 << 16);
  }

  const float* kl = kb + (size_t)l * NN * 8;
  const float* vl = vb + (size_t)l * NN * 8;
#pragma unroll
  for (int i = 0; i < 8; ++i) {
    const int idx = i * 512 + t;
    const int n = idx >> 3, j = idx & 7;
    ks[n*9 + j] = kl[idx];
    vs[n*9 + j] = vl[idx];
  }
  {
    float sxb = 0.f;
#pragma unroll
    for (int i = 0; i < 4; ++i)
      sxb += xbarP[((size_t)l * NCH + (h + 8 * i)) * DD + lane];
    red[h][lane] = sxb;
  }
  __syncthreads();
  if (t < DD) {
    const float sv = ((red[0][t] + red[1][t]) + (red[2][t] + red[3][t]))
                   + ((red[4][t] + red[5][t]) + (red[6][t] + red[7][t]));
    xbL[t] = sv * (1.f / NN);
  }
  __syncthreads();
  if (t < DD) {
    float acc = 0.f;
    for (int d = 0; d < DD; ++d) acc = fmaf(xbL[d], Wq[d*DD + t], acc);
    qs[t] = acc * 0.35355339059327373f;   // 1/sqrt(DH)
  }
  __syncthreads();

  float sc[8];
  float m = -1e30f;
#pragma unroll
  for (int i = 0; i < 8; ++i) {
    const int n = i * 64 + lane;
    float s = 0.f;
#pragma unroll
    for (int d = 0; d < 8; ++d) s = fmaf(qs[h*8 + d], ks[n*9 + d], s);
    sc[i] = s;
    m = fmaxf(m, s);
  }
#pragma unroll
  for (int off = 32; off; off >>= 1) m = fmaxf(m, __shfl_xor(m, off));
  float ssum = 0.f;
#pragma unroll
  for (int i = 0; i < 8; ++i) { sc[i] = __expf(sc[i] - m); ssum += sc[i]; }
#pragma unroll
  for (int off = 32; off; off >>= 1) ssum += __shfl_xor(ssum, off);
  const float inv = 1.f / ssum;

  float oacc[8];
#pragma unroll
  for (int d = 0; d < 8; ++d) oacc[d] = 0.f;
#pragma unroll
  for (int i = 0; i < 8; ++i) {
    const int n = i * 64 + lane;
#pragma unroll
    for (int d = 0; d < 8; ++d) oacc[d] = fmaf(sc[i], vs[n*9 + d], oacc[d]);
  }
#pragma unroll
  for (int d = 0; d < 8; ++d) {
#pragma unroll
    for (int off = 32; off; off >>= 1) oacc[d] += __shfl_xor(oacc[d], off);
  }
  if (lane == 0) {
#pragma unroll
    for (int d = 0; d < 8; ++d)
      obT[(size_t)(h * 8 + d) * LL + l] = oacc[d] * inv;
  }
}

// ---------------------------------------------------------------------------
// Kernel C v13: msa tile staged via global_load_lds DMA (32x 1KB, linear LDS,
// chunk-swizzled GLOBAL source: slot c holds global chunk c^(r&7) -> reads
// are 2-way bank-free). A-frags built from LDS + stats; the 32KB tile is
// then REUSED as TH/TL. 2-term mv1, inline obT gather (R16 position),
// sigmoid (rcp), t hi/lo swizzled, 3-term mv2. launch_bounds(256,4).
// ---------------------------------------------------------------------------
__global__ __launch_bounds__(256, 4) void kC(
    const float* __restrict__ msa, const float* __restrict__ stats,
    const float* __restrict__ lnw, const float* __restrict__ lnb,
    const unsigned* __restrict__ Bpk, const float* __restrict__ bg,
    const float* __restrict__ obT, const float* __restrict__ bout,
    float* __restrict__ out)
{
  __shared__ float Xs[128 * 64];             // 32 KB msa tile, reused as TH/TL
  unsigned short* TH = (unsigned short*)Xs;  // 16 KB
  unsigned short* TL = TH + 128 * 64;        // 16 KB
  const int t = threadIdx.x;
  const int lane = t & 63;
  const int w = t >> 6;
  const int rbase = 32 * w;
  const size_t R0 = (size_t)blockIdx.x * 128;

  const short8* Bp = (const short8*)Bpk;   // frag*64 + lane

  // ---- stage msa tile: 8 DMA instrs/wave, source chunk-swizzled ----
#pragma unroll
  for (int i = 0; i < 8; ++i) {
    const int rl = 32 * w + 4 * i + (lane >> 4);  // local row this lane feeds
    const int c  = (lane & 15) ^ (rl & 7);        // global 16B-chunk to fetch
    const float* src = msa + (R0 + rl) * DD + c * 4;
    __builtin_amdgcn_global_load_lds(
        (const __attribute__((address_space(1))) unsigned int*)src,
        (__attribute__((address_space(3))) unsigned int*)&Xs[(32 * w + 4 * i) * 64],
        16, 0, 0);
  }
  __syncthreads();   // DMA drained (vmcnt(0) before barrier)

  // ---- A-frags from LDS tile + stats ----
  f32x4 acc[2][4];
#pragma unroll
  for (int rt = 0; rt < 2; ++rt)
#pragma unroll
    for (int ct = 0; ct < 4; ++ct) acc[rt][ct] = f32x4{0.f, 0.f, 0.f, 0.f};

  short8 ah[2][2];
#pragma unroll
  for (int rt = 0; rt < 2; ++rt) {
    const int r = rbase + rt * 16 + (lane & 15);
    const float2 ab = *(const float2*)&stats[(R0 + r) * 2];
    const float aa = ab.x, bb = ab.y;
#pragma unroll
    for (int hh = 0; hh < 2; ++hh) {
      const int g0 = (lane >> 4) * 2 + hh * 8;    // 16B chunk index
      const int s0 = g0 ^ (r & 7);
      const int s1 = (g0 + 1) ^ (r & 7);
      const float4 f0 = *(const float4*)&Xs[r * 64 + s0 * 4];
      const float4 f1 = *(const float4*)&Xs[r * 64 + s1 * 4];
      const int d0 = g0 * 4;                      // element index kg + hh*32
      const float4 w0 = *(const float4*)&lnw[d0];
      const float4 w1 = *(const float4*)&lnw[d0 + 4];
      const float4 b0 = *(const float4*)&lnb[d0];
      const float4 b1 = *(const float4*)&lnb[d0 + 4];
      const unsigned q0 = cvtpk2(fmaf(fmaf(f0.x, aa, bb), w0.x, b0.x),
                                 fmaf(fmaf(f0.y, aa, bb), w0.y, b0.y));
      const unsigned q1 = cvtpk2(fmaf(fmaf(f0.z, aa, bb), w0.z, b0.z),
                                 fmaf(fmaf(f0.w, aa, bb), w0.w, b0.w));
      const unsigned q2 = cvtpk2(fmaf(fmaf(f1.x, aa, bb), w1.x, b1.x),
                                 fmaf(fmaf(f1.y, aa, bb), w1.y, b1.y));
      const unsigned q3 = cvtpk2(fmaf(fmaf(f1.z, aa, bb), w1.z, b1.z),
                                 fmaf(fmaf(f1.w, aa, bb), w1.w, b1.w));
      ah[rt][hh] = pack8(q0, q1, q2, q3);
    }
  }
  __syncthreads();   // all tile reads done before TH/TL overwrite

  // ---- mv1 (2-term) ----
#pragma unroll
  for (int ct = 0; ct < 4; ++ct) {
    const short8 bh0 = Bp[(0 * 8 + ct * 2 + 0) * 64 + lane];
    const short8 bh1 = Bp[(0 * 8 + ct * 2 + 1) * 64 + lane];
    const short8 bl0 = Bp[(1 * 8 + ct * 2 + 0) * 64 + lane];
    const short8 bl1 = Bp[(1 * 8 + ct * 2 + 1) * 64 + lane];
#pragma unroll
    for (int rt = 0; rt < 2; ++rt) {
      f32x4 c = acc[rt][ct];
      c = __builtin_amdgcn_mfma_f32_16x16x32_bf16(ah[rt][0], bh0, c, 0, 0, 0);
      c = __builtin_amdgcn_mfma_f32_16x16x32_bf16(ah[rt][1], bh1, c, 0, 0, 0);
      c = __builtin_amdgcn_mfma_f32_16x16x32_bf16(ah[rt][0], bl0, c, 0, 0, 0);
      c = __builtin_amdgcn_mfma_f32_16x16x32_bf16(ah[rt][1], bl1, c, 0, 0, 0);
      acc[rt][ct] = c;
    }
  }

  // ---- sigmoid * o -> t, hi/lo split into swizzled TH/TL (wave-private) ----
#pragma unroll
  for (int rt = 0; rt < 2; ++rt) {
    const int rl0 = rbase + rt * 16 + ((lane >> 4) << 2);
    const int li0 = (int)((R0 + rl0) & (LL - 1));
#pragma unroll
    for (int ct = 0; ct < 4; ++ct) {
      const int col = ct * 16 + (lane & 15);
      const float4 ov = *(const float4*)&obT[(size_t)col * LL + li0];
      const float bgc = bg[col];
      const float tv0 = ov.x * __builtin_amdgcn_rcpf(1.f + __expf(-(acc[rt][ct][0] + bgc)));
      const float tv1 = ov.y * __builtin_amdgcn_rcpf(1.f + __expf(-(acc[rt][ct][1] + bgc)));
      const float tv2 = ov.z * __builtin_amdgcn_rcpf(1.f + __expf(-(acc[rt][ct][2] + bgc)));
      const float tv3 = ov.w * __builtin_amdgcn_rcpf(1.f + __expf(-(acc[rt][ct][3] + bgc)));
      const unsigned ph01 = cvtpk2(tv0, tv1);
      const unsigned ph23 = cvtpk2(tv2, tv3);
      const float h0 = __uint_as_float(ph01 << 16);
      const float h1 = __uint_as_float(ph01 & 0xFFFF0000u);
      const float h2 = __uint_as_float(ph23 << 16);
      const float h3 = __uint_as_float(ph23 & 0xFFFF0000u);
      const unsigned pl01 = cvtpk2(tv0 - h0, tv1 - h1);
      const unsigned pl23 = cvtpk2(tv2 - h2, tv3 - h3);
      TH[swz(rl0 + 0, col)] = (unsigned short)ph01;
      TH[swz(rl0 + 1, col)] = (unsigned short)(ph01 >> 16);
      TH[swz(rl0 + 2, col)] = (unsigned short)ph23;
      TH[swz(rl0 + 3, col)] = (unsigned short)(ph23 >> 16);
      TL[swz(rl0 + 0, col)] = (unsigned short)pl01;
      TL[swz(rl0 + 1, col)] = (unsigned short)(pl01 >> 16);
      TL[swz(rl0 + 2, col)] = (unsigned short)pl23;
      TL[swz(rl0 + 3, col)] = (unsigned short)(pl23 >> 16);
    }
  }
  // no barrier: wave-private rows

  // ---- mv2: out = t @ Wout + bout (3-term) ----
#pragma unroll
  for (int rt = 0; rt < 2; ++rt)
#pragma unroll
    for (int ct = 0; ct < 4; ++ct) {
      const float bo = bout[ct * 16 + (lane & 15)];
      acc[rt][ct] = f32x4{bo, bo, bo, bo};
    }
  {
    short8 th[2][2], tl[2][2];
#pragma unroll
    for (int rt = 0; rt < 2; ++rt) {
      const int ar = rbase + rt * 16 + (lane & 15);
      const int kg = (lane >> 4) * 8;
      th[rt][0] = *(const short8*)&TH[swz(ar, kg)];
      th[rt][1] = *(const short8*)&TH[swz(ar, kg + 32)];
      tl[rt][0] = *(const short8*)&TL[swz(ar, kg)];
      tl[rt][1] = *(const short8*)&TL[swz(ar, kg + 32)];
    }
#pragma unroll
    for (int ct = 0; ct < 4; ++ct) {
      const short8 bh0 = Bp[(2 * 8 + ct * 2 + 0) * 64 + lane];
      const short8 bh1 = Bp[(2 * 8 + ct * 2 + 1) * 64 + lane];
      const short8 bl0 = Bp[(3 * 8 + ct * 2 + 0) * 64 + lane];
      const short8 bl1 = Bp[(3 * 8 + ct * 2 + 1) * 64 + lane];
#pragma unroll
      for (int rt = 0; rt < 2; ++rt) {
        f32x4 c = acc[rt][ct];
        c = __builtin_amdgcn_mfma_f32_16x16x32_bf16(th[rt][0], bh0, c, 0, 0, 0);
        c = __builtin_amdgcn_mfma_f32_16x16x32_bf16(th[rt][1], bh1, c, 0, 0, 0);
        c = __builtin_amdgcn_mfma_f32_16x16x32_bf16(th[rt][0], bl0, c, 0, 0, 0);
        c = __builtin_amdgcn_mfma_f32_16x16x32_bf16(th[rt][1], bl1, c, 0, 0, 0);
        c = __builtin_amdgcn_mfma_f32_16x16x32_bf16(tl[rt][0], bh0, c, 0, 0, 0);
        c = __builtin_amdgcn_mfma_f32_16x16x32_bf16(tl[rt][1], bh1, c, 0, 0, 0);
        acc[rt][ct] = c;
      }
    }
  }

#pragma unroll
  for (int rt = 0; rt < 2; ++rt) {
#pragma unroll
    for (int j = 0; j < 4; ++j) {
      const size_t rg = R0 + rbase + rt * 16 + ((lane >> 4) << 2) + j;
#pragma unroll
      for (int ct = 0; ct < 4; ++ct)
        out[rg * DD + ct * 16 + (lane & 15)] = acc[rt][ct][j];
    }
  }
}

// ---------------------------------------------------------------------------
extern "C" void kernel_launch(void* const* d_in, const int* in_sizes, int n_in,
                              void* d_out, int out_size, void* d_ws, size_t ws_size,
                              hipStream_t stream)
{
  const float* msa  = (const float*)d_in[0];
  const float* lnw  = (const float*)d_in[1];
  const float* lnb  = (const float*)d_in[2];
  const float* Wq   = (const float*)d_in[3];
  const float* Wk   = (const float*)d_in[4];
  const float* Wv   = (const float*)d_in[5];
  const float* Wg   = (const float*)d_in[6];
  const float* bg   = (const float*)d_in[7];
  const float* Wout = (const float*)d_in[8];
  const float* bout = (const float*)d_in[9];
  float* out = (float*)d_out;

  float* kb    = (float*)d_ws;                        // (L, N, 8)  16 MB
  float* vb    = kb + (size_t)LL * NN * 8;            // (L, N, 8)  16 MB
  float* xbarP = vb + (size_t)LL * NN * 8;            // (L, 32, 64) 8 MB
  float* obT   = xbarP + (size_t)LL * NCH * DD;       // (64, L)   256 KB
  unsigned* Bpk = (unsigned*)(obT + (size_t)DD * LL); // 32 KB packed weights
  float* stats = (float*)(Bpk + 8192);                // (N*L, 2)  4 MB

  kA<<<64 * NCH, 256, 0, stream>>>(msa, lnw, lnb, Wk, Wv, kb, vb, xbarP, stats);
  kB<<<LL, 512, 0, stream>>>(kb, vb, xbarP, Wq, Wg, Wout, Bpk, obT);
  kC<<<(NN * LL) / 128, 256, 0, stream>>>(msa, stats, lnw, lnb, Bpk, bg, obT, bout, out);
}